// Round 8
// baseline (274.491 us; speedup 1.0000x reference)
//
#include <hip/hip_runtime.h>
#include <cfloat>
#include <cmath>

#define VOCAB 8192
#define MTOT 16384
#define CDIM 256
#define KSPLIT 8
#define TAU 0.1f
#define IDX_INF 0x7fffffff

typedef __attribute__((ext_vector_type(8))) short bf16x8;
typedef __attribute__((ext_vector_type(4))) float f32x4;

#define AS1 __attribute__((address_space(1)))
#define AS3 __attribute__((address_space(3)))

__device__ __forceinline__ void gl_lds16(const void* g, void* l) {
  __builtin_amdgcn_global_load_lds((const AS1 unsigned int*)g,
                                   (AS3 unsigned int*)l, 16, 0, 0);
}

__device__ inline ushort f2bf(float f) {
  unsigned u = __float_as_uint(f);
  unsigned r = (u + 0x7fffu + ((u >> 16) & 1u)) >> 16;
  return (ushort)r;
}

// merge other top-2 (ob,oi,os,osi) into mine (b,i,s,si); order by (value, index)
__device__ inline void top2_merge(float& b, int& i, float& s, int& si,
                                  float ob, int oi, float os, int osi) {
  if (ob < b || (ob == b && oi < i)) {
    if (b < os || (b == os && i < osi)) { s = b; si = i; }
    else { s = os; si = osi; }
    b = ob; i = oi;
  } else {
    if (ob < s || (ob == s && oi < si)) { s = ob; si = oi; }
  }
}

// ---------------- enorm: ||e_k||^2 fp32 + exact fp64 ----------------
__global__ void vq_enorm_kernel(const float* __restrict__ emb,
                                float* __restrict__ enorm,
                                double* __restrict__ enormd) {
  __shared__ double sd[4][64];
  int tid = threadIdx.x;
  int kk = tid & 63, cg = tid >> 6;
  int k = blockIdx.x * 64 + kk;
  double s = 0.0;
  for (int c = cg * 64; c < cg * 64 + 64; ++c) {
    float v = emb[(size_t)c * VOCAB + k];
    s += (double)v * (double)v;
  }
  sd[cg][kk] = s;
  __syncthreads();
  if (cg == 0) {
    double t = sd[0][kk] + sd[1][kk] + sd[2][kk] + sd[3][kk];
    enorm[k] = (float)t;
    enormd[k] = t;
  }
}

// ---------------- fused: transpose emb -> embT fp32 AND emit eb bf16 granules ----------------
// eb granule layout (16B = 8 bf16 dims of one code):
//   ga = sp*32768 + (kt*8+cc)*1024 + r*8 + s
//   where code = sp*1024 + kt*256 + c_local, r = c_local>>1,
//   s = ((c_local&1)<<2) | ((g + r)&3), dims = cc*32 + g*8
__global__ void vq_prep_embT_kernel(const float* __restrict__ emb,
                                    float* __restrict__ embT,
                                    ushort* __restrict__ eb) {
  __shared__ float t[32][33];
  int bc = blockIdx.x & 7;    // dims block (cc)
  int bk = blockIdx.x >> 3;   // code block
  int lx = threadIdx.x & 31, lyq = threadIdx.x >> 5;
#pragma unroll
  for (int yy = 0; yy < 4; ++yy) {
    int y = lyq * 4 + yy;
    t[y][lx] = emb[(size_t)(bc * 32 + y) * VOCAB + bk * 32 + lx];
  }
  __syncthreads();
#pragma unroll
  for (int yy = 0; yy < 4; ++yy) {
    int y = lyq * 4 + yy;
    embT[(size_t)(bk * 32 + y) * CDIM + bc * 32 + lx] = t[lx][y];
  }
  // granule emission: 128 granules (32 codes x 4 g) for cc = bc
  if (threadIdx.x < 128) {
    int cx = threadIdx.x >> 2, g = threadIdx.x & 3;
    int k = bk * 32 + cx;
    int sp = k >> 10, kt = (k >> 8) & 3, c_local = k & 255;
    int r = c_local >> 1;
    int s = ((c_local & 1) << 2) | ((g + r) & 3);
    size_t ga = (size_t)sp * 32768 + (size_t)(kt * 8 + bc) * 1024 + r * 8 + s;
    bf16x8 h;
#pragma unroll
    for (int j = 0; j < 8; ++j) h[j] = (short)f2bf(t[g * 8 + j][cx]);
    *(bf16x8*)(eb + ga * 8) = h;
  }
}

// ---------------- pack -2x -> bf16 pair-swizzled strips ----------------
// granule u: rb=u>>11; q=u&2047; cc=q>>8; r=(q>>3)&31; s=q&7
// row = rb*64 + r*2 + (s>>2); g = ((s&3) - r)&3; dims = cc*32 + g*8
__global__ void vq_pack_x_kernel(const float* __restrict__ x,
                                 ushort* __restrict__ xb) {
  int u = blockIdx.x * 256 + threadIdx.x;
  int rb = u >> 11;
  int q = u & 2047;
  int cc = q >> 8, r = (q >> 3) & 31, s = q & 7;
  int row = rb * 64 + r * 2 + (s >> 2);
  int g = ((s & 3) - r) & 3;
  int dims = cc * 32 + g * 8;
  const float* src = x + (size_t)row * CDIM + dims;
  float4 v0 = *(const float4*)src;
  float4 v1 = *(const float4*)(src + 4);
  float a[8] = {v0.x, v0.y, v0.z, v0.w, v1.x, v1.y, v1.z, v1.w};
  bf16x8 h;
#pragma unroll
  for (int j = 0; j < 8; ++j) h[j] = (short)f2bf(-2.0f * a[j]);
  *(bf16x8*)(xb + (size_t)u * 8) = h;
}

// ---------------- bf16 MFMA distance: 64x64 wave tile, block-sync pipeline ----------------
// block = 4 waves (1x4 codes), tile 64 rows x 1024 codes (split sp).
// A resident 32KB, B streamed 256codes x 32dims (16KB) double-buffered.
// Pair-swizzle (2 rows per 128B line): conflict-free ds_read_b128.
__global__ __launch_bounds__(256, 2) void vq_dist_kernel(
    const ushort* __restrict__ xb, const ushort* __restrict__ eb,
    const float* __restrict__ enorm,
    float4* __restrict__ pkd, int4* __restrict__ pki) {
  __shared__ ushort Abuf[16384];        // 32 KB: [cc8][r32][s8] granules
  __shared__ ushort Bbuf[2][8192];      // 2 x 16 KB: [r128][s8]
  __shared__ float msd[2][4][64];
  __shared__ int msi[2][4][64];

  const int tid = threadIdx.x;
  const int lane = tid & 63, wc = tid >> 6;
  const int l15 = lane & 15, lg = lane >> 4;
  const int rb = blockIdx.x >> 3, sp = blockIdx.x & 7;
  const int m0 = rb * 64;

  const ushort* xs = xb + (size_t)rb * 16384;        // 2048 granules
  const ushort* ebb = eb + (size_t)sp * 262144;      // 32768 granules

  // prologue: A strip (32 segs of 1KB) + B chunk 0 (16 segs)
#pragma unroll
  for (int i = 0; i < 8; ++i)
    gl_lds16(xs + (wc * 8 + i) * 512 + lane * 8, &Abuf[(wc * 8 + i) * 512]);
#pragma unroll
  for (int i = 0; i < 4; ++i)
    gl_lds16(ebb + (wc * 4 + i) * 512 + lane * 8, &Bbuf[0][(wc * 4 + i) * 512]);

  // enorm prefetch for this wave's 16 code-columns per kt
  float en[4][4];
#pragma unroll
  for (int kt = 0; kt < 4; ++kt)
#pragma unroll
    for (int nf = 0; nf < 4; ++nf)
      en[kt][nf] = enorm[sp * 1024 + kt * 256 + wc * 64 + nf * 16 + l15];

  // hoisted LDS byte offsets (pair-swizzle: s = ((idx&1)<<2) | ((lg + idx>>1)&3))
  uint offA[4], offB[4];
#pragma unroll
  for (int mf = 0; mf < 4; ++mf) {
    int row = mf * 16 + l15;
    int r = row >> 1;
    int s = ((row & 1) << 2) | ((lg + r) & 3);
    offA[mf] = r * 128 + s * 16;
  }
#pragma unroll
  for (int nf = 0; nf < 4; ++nf) {
    int c = wc * 64 + nf * 16 + l15;
    int r = c >> 1;
    int s = ((c & 1) << 2) | ((lg + r) & 3);
    offB[nf] = r * 128 + s * 16;
  }

  float bv[16];
  int bi[16];
#pragma unroll
  for (int s = 0; s < 16; ++s) { bv[s] = FLT_MAX; bi[s] = 0; }

#pragma unroll
  for (int kt = 0; kt < 4; ++kt) {
    f32x4 acc[4][4];
#pragma unroll
    for (int mf = 0; mf < 4; ++mf)
#pragma unroll
      for (int nf = 0; nf < 4; ++nf) {
        float e = en[kt][nf];
        acc[mf][nf] = (f32x4){e, e, e, e};
      }
#pragma unroll
    for (int cc = 0; cc < 8; ++cc) {
      const int t = kt * 8 + cc;
      __syncthreads();   // chunk t resident (barrier drains vmcnt); prev reads done
      if (t < 31) {      // stage chunk t+1 into the other buffer
        const ushort* src = ebb + (size_t)(t + 1) * 8192;
        ushort* dst = &Bbuf[(t + 1) & 1][0];
#pragma unroll
        for (int i = 0; i < 4; ++i)
          gl_lds16(src + (wc * 4 + i) * 512 + lane * 8, dst + (wc * 4 + i) * 512);
      }
      const char* Ab = (const char*)Abuf + cc * 4096;
      const char* Bb = (const char*)&Bbuf[t & 1][0];
      bf16x8 af[4], bfr[4];
#pragma unroll
      for (int mf = 0; mf < 4; ++mf) af[mf] = *(const bf16x8*)(Ab + offA[mf]);
#pragma unroll
      for (int nf = 0; nf < 4; ++nf) bfr[nf] = *(const bf16x8*)(Bb + offB[nf]);
#pragma unroll
      for (int mf = 0; mf < 4; ++mf)
#pragma unroll
        for (int nf = 0; nf < 4; ++nf)
          acc[mf][nf] = __builtin_amdgcn_mfma_f32_16x16x32_bf16(af[mf], bfr[nf], acc[mf][nf], 0, 0, 0);
    }
    // fold kt's distances into per-stream minima (strict < = first occurrence)
#pragma unroll
    for (int nf = 0; nf < 4; ++nf) {
      int n = sp * 1024 + kt * 256 + wc * 64 + nf * 16 + l15;
#pragma unroll
      for (int mf = 0; mf < 4; ++mf)
#pragma unroll
        for (int r = 0; r < 4; ++r) {
          float d = acc[mf][nf][r];
          int s = mf * 4 + r;
          if (d < bv[s]) { bv[s] = d; bi[s] = n; }
        }
    }
  }

  // per-row top-2 across the 16 column-lanes (in-register)
#pragma unroll
  for (int mf = 0; mf < 4; ++mf)
#pragma unroll
    for (int r = 0; r < 4; ++r) {
      int s = mf * 4 + r;
      float b = bv[s], sec = FLT_MAX;
      int i = bi[s], si = IDX_INF;
#pragma unroll
      for (int m = 1; m < 16; m <<= 1) {
        float ob = __shfl_xor(b, m, 64);
        float os = __shfl_xor(sec, m, 64);
        int oi = __shfl_xor(i, m, 64);
        int osi = __shfl_xor(si, m, 64);
        top2_merge(b, i, sec, si, ob, oi, os, osi);
      }
      if (l15 == 0) {
        int row = mf * 16 + lg * 4 + r;
        msd[0][wc][row] = b; msi[0][wc][row] = i;
        msd[1][wc][row] = sec; msi[1][wc][row] = si;
      }
    }
  __syncthreads();
  if (tid < 64) {
    float d[4] = {FLT_MAX, FLT_MAX, FLT_MAX, FLT_MAX};
    int ix[4] = {IDX_INF, IDX_INF, IDX_INF, IDX_INF};
#pragma unroll
    for (int w = 0; w < 4; ++w)
#pragma unroll
      for (int e = 0; e < 2; ++e) {
        float a = msd[e][w][tid];
        int ai = msi[e][w][tid];
#pragma unroll
        for (int q = 0; q < 4; ++q) {
          bool lt = (a < d[q]) || (a == d[q] && ai < ix[q]);
          float td = lt ? d[q] : a;
          int ti = lt ? ix[q] : ai;
          d[q] = lt ? a : d[q];
          ix[q] = lt ? ai : ix[q];
          a = td; ai = ti;
        }
      }
    pkd[(size_t)sp * MTOT + m0 + tid] = make_float4(d[0], d[1], d[2], d[3]);
    pki[(size_t)sp * MTOT + m0 + tid] = make_int4(ix[0], ix[1], ix[2], ix[3]);
  }
}

// ---------------- merge 32 candidates + fp64 rescue + gather (1 wave / row) ----------------
__global__ void vq_gather_kernel(
    const float* __restrict__ x, const float* __restrict__ embT,
    const double* __restrict__ enormd,
    const float4* __restrict__ pkd, const int4* __restrict__ pki,
    float* __restrict__ out, int* __restrict__ counts, float* __restrict__ ssep) {
  const int wid = threadIdx.x >> 6, lane = threadIdx.x & 63;
  const int m = blockIdx.x * 4 + wid;

  const float4 xq = *(const float4*)(x + (size_t)m * CDIM + lane * 4);

  float bd = FLT_MAX, sd = FLT_MAX;
  int bidx = IDX_INF;
#pragma unroll
  for (int sp2 = 0; sp2 < KSPLIT; ++sp2) {
    float4 dv = pkd[(size_t)sp2 * MTOT + m];
    int4 iv = pki[(size_t)sp2 * MTOT + m];
    float ds[4] = {dv.x, dv.y, dv.z, dv.w};
    int is[4] = {iv.x, iv.y, iv.z, iv.w};
#pragma unroll
    for (int j = 0; j < 4; ++j) {
      float dj = ds[j];
      int ij = is[j];
      if (dj < bd || (dj == bd && ij < bidx)) { sd = bd; bd = dj; bidx = ij; }
      else sd = fminf(sd, dj);
    }
  }
  int best = bidx;
  if (sd - bd < TAU) {   // ambiguous: exact fp64 over all 32 candidates (wave-uniform)
    double bD = DBL_MAX;
    int bn = IDX_INF;
    for (int sp2 = 0; sp2 < KSPLIT; ++sp2) {
      int4 iv = pki[(size_t)sp2 * MTOT + m];
      int is[4] = {iv.x, iv.y, iv.z, iv.w};
#pragma unroll
      for (int j = 0; j < 4; ++j) {
        int cj = is[j];
        const float4 ev = *(const float4*)(embT + (size_t)cj * CDIM + lane * 4);
        double p = (double)xq.x * ev.x + (double)xq.y * ev.y
                 + (double)xq.z * ev.z + (double)xq.w * ev.w;
#pragma unroll
        for (int off = 1; off < 64; off <<= 1) p += __shfl_xor(p, off, 64);
        double dj = enormd[cj] - 2.0 * p;
        if (dj < bD || (dj == bD && cj < bn)) { bD = dj; bn = cj; }
      }
    }
    best = bn;
  }
  const float4 ev = *(const float4*)(embT + (size_t)best * CDIM + lane * 4);
  *(float4*)(out + (size_t)m * CDIM + lane * 4) = ev;
  float dx = ev.x - xq.x, dy = ev.y - xq.y, dz = ev.z - xq.z, dw = ev.w - xq.w;
  float v = dx * dx + dy * dy + dz * dz + dw * dw;
#pragma unroll
  for (int off = 32; off > 0; off >>= 1) v += __shfl_down(v, off, 64);
  if (lane == 0) {
    ssep[m] = v;
    atomicAdd(&counts[best], 1);
  }
}

// ---------------- loss + perplexity, two-stage deterministic ----------------
__global__ void vq_final1_kernel(const float* __restrict__ ssep,
                                 const int* __restrict__ counts,
                                 double* __restrict__ part) {
  __shared__ double red[256];
  const int tid = threadIdx.x, b = blockIdx.x;
  red[tid] = (double)ssep[b * 256 + tid];
  __syncthreads();
  for (int off = 128; off > 0; off >>= 1) {
    if (tid < off) red[tid] += red[tid + off];
    __syncthreads();
  }
  if (tid == 0) part[b] = red[0];
  __syncthreads();
  double e = 0.0;
  if (tid < 128) {
    double p = (double)counts[b * 128 + tid] / (double)MTOT;
    e = p * log(p + 1e-10);
  }
  red[tid] = e;
  __syncthreads();
  for (int off = 128; off > 0; off >>= 1) {
    if (tid < off) red[tid] += red[tid + off];
    __syncthreads();
  }
  if (tid == 0) part[64 + b] = red[0];
}

__global__ void vq_final2_kernel(const double* __restrict__ part,
                                 float* __restrict__ out) {
  const int lane = threadIdx.x;   // 64 threads
  double s = part[lane], e = part[64 + lane];
#pragma unroll
  for (int off = 32; off > 0; off >>= 1) {
    s += __shfl_down(s, off, 64);
    e += __shfl_down(e, off, 64);
  }
  if (lane == 0) {
    out[(size_t)MTOT * CDIM] = (float)(1.25 * s / (double)((size_t)MTOT * CDIM));
    out[(size_t)MTOT * CDIM + 1] = (float)exp(-e);
  }
}

extern "C" void kernel_launch(void* const* d_in, const int* in_sizes, int n_in,
                              void* d_out, int out_size, void* d_ws, size_t ws_size,
                              hipStream_t stream) {
  const float* x = (const float*)d_in[0];
  const float* emb = (const float*)d_in[1];
  float* out = (float*)d_out;
  char* ws = (char*)d_ws;

  // workspace layout (bytes)
  double* enormd = (double*)(ws);                 //        0: 65536
  float* enorm   = (float*)(ws + 65536);          //    65536: 32768
  float4* pkd    = (float4*)(ws + 98304);         //    98304: 2097152
  int4* pki      = (int4*)(ws + 2195456);         //  2195456: 2097152
  int* counts    = (int*)(ws + 4292608);          //  4292608: 32768
  float* ssep    = (float*)(ws + 4325376);        //  4325376: 65536
  double* part   = (double*)(ws + 4390912);       //  4390912: 1024
  float* embT    = (float*)(ws + 4391936);        //  4391936: 8388608
  ushort* xb     = (ushort*)(ws + 12780544);      // 12780544: 8388608
  ushort* eb     = (ushort*)(ws + 21169152);      // 21169152: 4194304
  // total 25363456 bytes (< 35 MB proven available in rounds 1-7)

  hipMemsetAsync(counts, 0, VOCAB * sizeof(int), stream);
  vq_enorm_kernel<<<VOCAB / 64, 256, 0, stream>>>(emb, enorm, enormd);
  vq_prep_embT_kernel<<<(VOCAB / 32) * (CDIM / 32), 256, 0, stream>>>(emb, embT, eb);
  vq_pack_x_kernel<<<(MTOT * CDIM / 8) / 256, 256, 0, stream>>>(x, xb);
  vq_dist_kernel<<<(MTOT / 64) * KSPLIT, 256, 0, stream>>>(xb, eb, enorm, pkd, pki);
  vq_gather_kernel<<<MTOT / 4, 256, 0, stream>>>(x, embT, enormd, pkd, pki,
                                                 out, counts, ssep);
  vq_final1_kernel<<<64, 256, 0, stream>>>(ssep, counts, part);
  vq_final2_kernel<<<1, 64, 0, stream>>>(part, out);
}

// Round 9
// 240.726 us; speedup vs baseline: 1.1403x; 1.1403x over previous
//
#include <hip/hip_runtime.h>
#include <cfloat>
#include <cmath>

#define VOCAB 8192
#define MTOT 16384
#define CDIM 256
#define KSPLIT 8
#define TAU 0.1f
#define IDX_INF 0x7fffffff

typedef __attribute__((ext_vector_type(8))) short bf16x8;
typedef __attribute__((ext_vector_type(4))) float f32x4;

#define AS1 __attribute__((address_space(1)))
#define AS3 __attribute__((address_space(3)))

__device__ __forceinline__ void gl_lds16(const void* g, void* l) {
  __builtin_amdgcn_global_load_lds((const AS1 unsigned int*)g,
                                   (AS3 unsigned int*)l, 16, 0, 0);
}

__device__ inline ushort f2bf(float f) {
  unsigned u = __float_as_uint(f);
  unsigned r = (u + 0x7fffu + ((u >> 16) & 1u)) >> 16;
  return (ushort)r;
}

// merge other top-2 (ob,oi,os,osi) into mine (b,i,s,si); order by (value, index)
__device__ inline void top2_merge(float& b, int& i, float& s, int& si,
                                  float ob, int oi, float os, int osi) {
  if (ob < b || (ob == b && oi < i)) {
    if (b < os || (b == os && i < osi)) { s = b; si = i; }
    else { s = os; si = osi; }
    b = ob; i = oi;
  } else {
    if (ob < s || (ob == s && oi < si)) { s = ob; si = oi; }
  }
}

// ---------------- enorm: ||e_k||^2 fp32 + exact fp64 ----------------
__global__ void vq_enorm_kernel(const float* __restrict__ emb,
                                float* __restrict__ enorm,
                                double* __restrict__ enormd) {
  __shared__ double sd[4][64];
  int tid = threadIdx.x;
  int kk = tid & 63, cg = tid >> 6;
  int k = blockIdx.x * 64 + kk;
  double s = 0.0;
  for (int c = cg * 64; c < cg * 64 + 64; ++c) {
    float v = emb[(size_t)c * VOCAB + k];
    s += (double)v * (double)v;
  }
  sd[cg][kk] = s;
  __syncthreads();
  if (cg == 0) {
    double t = sd[0][kk] + sd[1][kk] + sd[2][kk] + sd[3][kk];
    enorm[k] = (float)t;
    enormd[k] = t;
  }
}

// ---------------- fused: transpose emb -> embT fp32 AND emit eb bf16 granules ----------------
// eb chunk layout: per sp 64 chunks (kt*8+cc) of 512 granules (8 KB each).
// granule (r, s) of chunk holds code c_local = r*2 + (s>>2) (within the kt's 128
// codes), dims-group g = ((s&3) - r)&3, dims = cc*32 + g*8.
__global__ void vq_prep_embT_kernel(const float* __restrict__ emb,
                                    float* __restrict__ embT,
                                    ushort* __restrict__ eb) {
  __shared__ float t[32][33];
  int bc = blockIdx.x & 7;    // dims block (cc)
  int bk = blockIdx.x >> 3;   // code block
  int lx = threadIdx.x & 31, lyq = threadIdx.x >> 5;
#pragma unroll
  for (int yy = 0; yy < 4; ++yy) {
    int y = lyq * 4 + yy;
    t[y][lx] = emb[(size_t)(bc * 32 + y) * VOCAB + bk * 32 + lx];
  }
  __syncthreads();
#pragma unroll
  for (int yy = 0; yy < 4; ++yy) {
    int y = lyq * 4 + yy;
    embT[(size_t)(bk * 32 + y) * CDIM + bc * 32 + lx] = t[lx][y];
  }
  // granule emission: 128 granules (32 codes x 4 g) for cc = bc
  if (threadIdx.x < 128) {
    int cx = threadIdx.x >> 2, g = threadIdx.x & 3;
    int k = bk * 32 + cx;
    int sp = k >> 10, c_sp = k & 1023;
    int kt = c_sp >> 7, c_local = c_sp & 127;
    int r = c_local >> 1;
    int s = ((c_local & 1) << 2) | ((g + r) & 3);
    size_t ga = (size_t)sp * 32768 + (size_t)(kt * 8 + bc) * 512 + r * 8 + s;
    bf16x8 h;
#pragma unroll
    for (int j = 0; j < 8; ++j) h[j] = (short)f2bf(t[g * 8 + j][cx]);
    *(bf16x8*)(eb + ga * 8) = h;
  }
}

// ---------------- pack -2x -> bf16 pair-swizzled strips (r8 layout, 0 conflicts) ----------------
// granule u: rb=u>>11; q=u&2047; cc=q>>8; r=(q>>3)&31; s=q&7
// row = rb*64 + r*2 + (s>>2); g = ((s&3) - r)&3; dims = cc*32 + g*8
__global__ void vq_pack_x_kernel(const float* __restrict__ x,
                                 ushort* __restrict__ xb) {
  int u = blockIdx.x * 256 + threadIdx.x;
  int rb = u >> 11;
  int q = u & 2047;
  int cc = q >> 8, r = (q >> 3) & 31, s = q & 7;
  int row = rb * 64 + r * 2 + (s >> 2);
  int g = ((s & 3) - r) & 3;
  int dims = cc * 32 + g * 8;
  const float* src = x + (size_t)row * CDIM + dims;
  float4 v0 = *(const float4*)src;
  float4 v1 = *(const float4*)(src + 4);
  float a[8] = {v0.x, v0.y, v0.z, v0.w, v1.x, v1.y, v1.z, v1.w};
  bf16x8 h;
#pragma unroll
  for (int j = 0; j < 8; ++j) h[j] = (short)f2bf(-2.0f * a[j]);
  *(bf16x8*)(xb + (size_t)u * 8) = h;
}

// ---------------- bf16 MFMA distance: counted-vmcnt ring pipeline ----------------
// block = 4 waves (2x2), tile 64 rows x 1024 codes (split sp). A resident 32KB.
// B streamed as 8KB chunks (128 codes x 32 dims), 4-slot ring, depth-3 prefetch.
// Raw s_barrier + per-wave s_waitcnt vmcnt(4): loads stay in flight across barriers.
__global__ __launch_bounds__(256, 2) void vq_dist_kernel(
    const ushort* __restrict__ xb, const ushort* __restrict__ eb,
    const float* __restrict__ enorm,
    float4* __restrict__ pkd, int4* __restrict__ pki) {
  __shared__ ushort Abuf[16384];        // 32 KB: [cc8][r32][s8] granules
  __shared__ ushort Bbuf[4][4096];      // ring: 4 x 8 KB: [r64][s8]
  __shared__ float msd[2][4][64];
  __shared__ int msi[2][4][64];

  const int tid = threadIdx.x;
  const int lane = tid & 63, wid = tid >> 6;
  const int wr = wid >> 1, wc = wid & 1;   // 2x2 wave grid
  const int l15 = lane & 15, lg = lane >> 4;
  const int rb = blockIdx.x >> 3, sp = blockIdx.x & 7;
  const int m0 = rb * 64;

  const ushort* xs = xb + (size_t)rb * 16384;     // 32 KB A strip
  const ushort* ebb = eb + (size_t)sp * 262144;   // 512 KB: 64 chunks x 4096 ushorts

  // enorm preload (issued FIRST -> oldest VMEM, drained by prologue wait)
  float en_s[8][4];
#pragma unroll
  for (int kt = 0; kt < 8; ++kt)
#pragma unroll
    for (int nf = 0; nf < 4; ++nf)
      en_s[kt][nf] = enorm[sp * 1024 + kt * 128 + wc * 64 + nf * 16 + l15];
  __builtin_amdgcn_sched_barrier(0);

  // prologue staging: A (8 insts/wave) + chunks 0..2 (2 insts each)
#pragma unroll
  for (int i = 0; i < 8; ++i)
    gl_lds16(xs + (wid * 8 + i) * 512 + lane * 8, &Abuf[(wid * 8 + i) * 512]);
#pragma unroll
  for (int c = 0; c < 3; ++c)
#pragma unroll
    for (int i = 0; i < 2; ++i)
      gl_lds16(ebb + c * 4096 + (wid * 2 + i) * 512 + lane * 8,
               &Bbuf[c][(wid * 2 + i) * 512]);
  __builtin_amdgcn_sched_barrier(0);
  asm volatile("s_waitcnt vmcnt(4)" ::: "memory");  // en+A+chunk0 done; c1,c2 in flight
  __builtin_amdgcn_s_barrier();
  __builtin_amdgcn_sched_barrier(0);

  // hoisted LDS byte offsets (pair-swizzle, measured conflict-free in r8)
  uint offA[2], offB[4];
#pragma unroll
  for (int mf = 0; mf < 2; ++mf) {
    int row = wr * 32 + mf * 16 + l15;
    int r = row >> 1;
    int s = ((row & 1) << 2) | ((lg + r) & 3);
    offA[mf] = r * 128 + s * 16;
  }
#pragma unroll
  for (int nf = 0; nf < 4; ++nf) {
    int c = wc * 64 + nf * 16 + l15;
    int r = c >> 1;
    int s = ((c & 1) << 2) | ((lg + r) & 3);
    offB[nf] = r * 128 + s * 16;
  }

  float bv[8];
  int bi[8];
#pragma unroll
  for (int s = 0; s < 8; ++s) { bv[s] = FLT_MAX; bi[s] = 0; }

  f32x4 acc[2][4];

#pragma unroll
  for (int kt = 0; kt < 8; ++kt) {
#pragma unroll
    for (int cc = 0; cc < 8; ++cc) {
      const int t = kt * 8 + cc;
      // issue staging of chunk t+3 into ring slot (t+3)&3 (last read at iter t-1,
      // separated by a barrier -> overwrite-safe)
      if (t + 3 < 64) {
        const ushort* src = ebb + (size_t)(t + 3) * 4096;
        ushort* dst = &Bbuf[(t + 3) & 3][0];
#pragma unroll
        for (int i = 0; i < 2; ++i)
          gl_lds16(src + (wid * 2 + i) * 512 + lane * 8, dst + (wid * 2 + i) * 512);
      }
      if (cc == 0) {
#pragma unroll
        for (int mf = 0; mf < 2; ++mf)
#pragma unroll
          for (int nf = 0; nf < 4; ++nf) {
            float e = en_s[kt][nf];
            acc[mf][nf] = (f32x4){e, e, e, e};
          }
      }
      const char* Ab = (const char*)Abuf + cc * 4096;
      const char* Bb = (const char*)&Bbuf[t & 3][0];
      bf16x8 af[2], bfr[4];
#pragma unroll
      for (int mf = 0; mf < 2; ++mf) af[mf] = *(const bf16x8*)(Ab + offA[mf]);
#pragma unroll
      for (int nf = 0; nf < 4; ++nf) bfr[nf] = *(const bf16x8*)(Bb + offB[nf]);
#pragma unroll
      for (int mf = 0; mf < 2; ++mf)
#pragma unroll
        for (int nf = 0; nf < 4; ++nf)
          acc[mf][nf] = __builtin_amdgcn_mfma_f32_16x16x32_bf16(af[mf], bfr[nf], acc[mf][nf], 0, 0, 0);
      if (cc == 7) {
        // fold kt's distances into per-stream minima (strict < = first occurrence)
#pragma unroll
        for (int nf = 0; nf < 4; ++nf) {
          int n = sp * 1024 + kt * 128 + wc * 64 + nf * 16 + l15;
#pragma unroll
          for (int mf = 0; mf < 2; ++mf)
#pragma unroll
            for (int r = 0; r < 4; ++r) {
              float d = acc[mf][nf][r];
              int s = mf * 4 + r;
              if (d < bv[s]) { bv[s] = d; bi[s] = n; }
            }
        }
      }
      // counted wait: chunk t+1 resident for next iter; keep t+2,t+3 in flight
      if (t <= 60) {
        asm volatile("s_waitcnt vmcnt(4) lgkmcnt(0)" ::: "memory");
      } else if (t == 61) {
        asm volatile("s_waitcnt vmcnt(2) lgkmcnt(0)" ::: "memory");
      } else if (t == 62) {
        asm volatile("s_waitcnt vmcnt(0) lgkmcnt(0)" ::: "memory");
      } else {
        asm volatile("s_waitcnt lgkmcnt(0)" ::: "memory");
      }
      __builtin_amdgcn_sched_barrier(0);
      __builtin_amdgcn_s_barrier();
      __builtin_amdgcn_sched_barrier(0);
    }
  }

  // per-stream top-2 across the 16 column-lanes (in-register)
#pragma unroll
  for (int mf = 0; mf < 2; ++mf)
#pragma unroll
    for (int r = 0; r < 4; ++r) {
      int s = mf * 4 + r;
      float b = bv[s], sec = FLT_MAX;
      int i = bi[s], si = IDX_INF;
#pragma unroll
      for (int m = 1; m < 16; m <<= 1) {
        float ob = __shfl_xor(b, m, 64);
        float os = __shfl_xor(sec, m, 64);
        int oi = __shfl_xor(i, m, 64);
        int osi = __shfl_xor(si, m, 64);
        top2_merge(b, i, sec, si, ob, oi, os, osi);
      }
      if (l15 == 0) {
        int row = wr * 32 + mf * 16 + lg * 4 + r;
        msd[0][wid][row] = b; msi[0][wid][row] = i;
        msd[1][wid][row] = sec; msi[1][wid][row] = si;
      }
    }
  __syncthreads();
  if (tid < 64) {
    int wrr = tid >> 5;          // which wave-row owns this row
    float d[4] = {FLT_MAX, FLT_MAX, FLT_MAX, FLT_MAX};
    int ix[4] = {IDX_INF, IDX_INF, IDX_INF, IDX_INF};
#pragma unroll
    for (int w2 = 0; w2 < 2; ++w2)
#pragma unroll
      for (int e = 0; e < 2; ++e) {
        float a = msd[e][wrr * 2 + w2][tid];
        int ai = msi[e][wrr * 2 + w2][tid];
#pragma unroll
        for (int q = 0; q < 4; ++q) {
          bool lt = (a < d[q]) || (a == d[q] && ai < ix[q]);
          float td = lt ? d[q] : a;
          int ti = lt ? ix[q] : ai;
          d[q] = lt ? a : d[q];
          ix[q] = lt ? ai : ix[q];
          a = td; ai = ti;
        }
      }
    pkd[(size_t)sp * MTOT + m0 + tid] = make_float4(d[0], d[1], d[2], d[3]);
    pki[(size_t)sp * MTOT + m0 + tid] = make_int4(ix[0], ix[1], ix[2], ix[3]);
  }
}

// ---------------- merge 32 candidates + fp64 rescue + gather (1 wave / row) ----------------
__global__ void vq_gather_kernel(
    const float* __restrict__ x, const float* __restrict__ embT,
    const double* __restrict__ enormd,
    const float4* __restrict__ pkd, const int4* __restrict__ pki,
    float* __restrict__ out, int* __restrict__ counts, float* __restrict__ ssep) {
  const int wid = threadIdx.x >> 6, lane = threadIdx.x & 63;
  const int m = blockIdx.x * 4 + wid;

  const float4 xq = *(const float4*)(x + (size_t)m * CDIM + lane * 4);

  float bd = FLT_MAX, sd = FLT_MAX;
  int bidx = IDX_INF;
#pragma unroll
  for (int sp2 = 0; sp2 < KSPLIT; ++sp2) {
    float4 dv = pkd[(size_t)sp2 * MTOT + m];
    int4 iv = pki[(size_t)sp2 * MTOT + m];
    float ds[4] = {dv.x, dv.y, dv.z, dv.w};
    int is[4] = {iv.x, iv.y, iv.z, iv.w};
#pragma unroll
    for (int j = 0; j < 4; ++j) {
      float dj = ds[j];
      int ij = is[j];
      if (dj < bd || (dj == bd && ij < bidx)) { sd = bd; bd = dj; bidx = ij; }
      else sd = fminf(sd, dj);
    }
  }
  int best = bidx;
  if (sd - bd < TAU) {   // ambiguous: exact fp64 over all 32 candidates (wave-uniform)
    double bD = DBL_MAX;
    int bn = IDX_INF;
    for (int sp2 = 0; sp2 < KSPLIT; ++sp2) {
      int4 iv = pki[(size_t)sp2 * MTOT + m];
      int is[4] = {iv.x, iv.y, iv.z, iv.w};
#pragma unroll
      for (int j = 0; j < 4; ++j) {
        int cj = is[j];
        const float4 ev = *(const float4*)(embT + (size_t)cj * CDIM + lane * 4);
        double p = (double)xq.x * ev.x + (double)xq.y * ev.y
                 + (double)xq.z * ev.z + (double)xq.w * ev.w;
#pragma unroll
        for (int off = 1; off < 64; off <<= 1) p += __shfl_xor(p, off, 64);
        double dj = enormd[cj] - 2.0 * p;
        if (dj < bD || (dj == bD && cj < bn)) { bD = dj; bn = cj; }
      }
    }
    best = bn;
  }
  const float4 ev = *(const float4*)(embT + (size_t)best * CDIM + lane * 4);
  *(float4*)(out + (size_t)m * CDIM + lane * 4) = ev;
  float dx = ev.x - xq.x, dy = ev.y - xq.y, dz = ev.z - xq.z, dw = ev.w - xq.w;
  float v = dx * dx + dy * dy + dz * dz + dw * dw;
#pragma unroll
  for (int off = 32; off > 0; off >>= 1) v += __shfl_down(v, off, 64);
  if (lane == 0) {
    ssep[m] = v;
    atomicAdd(&counts[best], 1);
  }
}

// ---------------- loss + perplexity, two-stage deterministic ----------------
__global__ void vq_final1_kernel(const float* __restrict__ ssep,
                                 const int* __restrict__ counts,
                                 double* __restrict__ part) {
  __shared__ double red[256];
  const int tid = threadIdx.x, b = blockIdx.x;
  red[tid] = (double)ssep[b * 256 + tid];
  __syncthreads();
  for (int off = 128; off > 0; off >>= 1) {
    if (tid < off) red[tid] += red[tid + off];
    __syncthreads();
  }
  if (tid == 0) part[b] = red[0];
  __syncthreads();
  double e = 0.0;
  if (tid < 128) {
    double p = (double)counts[b * 128 + tid] / (double)MTOT;
    e = p * log(p + 1e-10);
  }
  red[tid] = e;
  __syncthreads();
  for (int off = 128; off > 0; off >>= 1) {
    if (tid < off) red[tid] += red[tid + off];
    __syncthreads();
  }
  if (tid == 0) part[64 + b] = red[0];
}

__global__ void vq_final2_kernel(const double* __restrict__ part,
                                 float* __restrict__ out) {
  const int lane = threadIdx.x;   // 64 threads
  double s = part[lane], e = part[64 + lane];
#pragma unroll
  for (int off = 32; off > 0; off >>= 1) {
    s += __shfl_down(s, off, 64);
    e += __shfl_down(e, off, 64);
  }
  if (lane == 0) {
    out[(size_t)MTOT * CDIM] = (float)(1.25 * s / (double)((size_t)MTOT * CDIM));
    out[(size_t)MTOT * CDIM + 1] = (float)exp(-e);
  }
}

extern "C" void kernel_launch(void* const* d_in, const int* in_sizes, int n_in,
                              void* d_out, int out_size, void* d_ws, size_t ws_size,
                              hipStream_t stream) {
  const float* x = (const float*)d_in[0];
  const float* emb = (const float*)d_in[1];
  float* out = (float*)d_out;
  char* ws = (char*)d_ws;

  // workspace layout (bytes)
  double* enormd = (double*)(ws);                 //        0: 65536
  float* enorm   = (float*)(ws + 65536);          //    65536: 32768
  float4* pkd    = (float4*)(ws + 98304);         //    98304: 2097152
  int4* pki      = (int4*)(ws + 2195456);         //  2195456: 2097152
  int* counts    = (int*)(ws + 4292608);          //  4292608: 32768
  float* ssep    = (float*)(ws + 4325376);        //  4325376: 65536
  double* part   = (double*)(ws + 4390912);       //  4390912: 1024
  float* embT    = (float*)(ws + 4391936);        //  4391936: 8388608
  ushort* xb     = (ushort*)(ws + 12780544);      // 12780544: 8388608
  ushort* eb     = (ushort*)(ws + 21169152);      // 21169152: 4194304
  // total 25363456 bytes (< 35 MB proven available in rounds 1-8)

  hipMemsetAsync(counts, 0, VOCAB * sizeof(int), stream);
  vq_enorm_kernel<<<VOCAB / 64, 256, 0, stream>>>(emb, enorm, enormd);
  vq_prep_embT_kernel<<<(VOCAB / 32) * (CDIM / 32), 256, 0, stream>>>(emb, embT, eb);
  vq_pack_x_kernel<<<(MTOT * CDIM / 8) / 256, 256, 0, stream>>>(x, xb);
  vq_dist_kernel<<<(MTOT / 64) * KSPLIT, 256, 0, stream>>>(xb, eb, enorm, pkd, pki);
  vq_gather_kernel<<<MTOT / 4, 256, 0, stream>>>(x, embT, enormd, pkd, pki,
                                                 out, counts, ssep);
  vq_final1_kernel<<<64, 256, 0, stream>>>(ssep, counts, part);
  vq_final2_kernel<<<1, 64, 0, stream>>>(part, out);
}

// Round 10
// 226.570 us; speedup vs baseline: 1.2115x; 1.0625x over previous
//
#include <hip/hip_runtime.h>
#include <cfloat>
#include <cmath>

#define VOCAB 8192
#define MTOT 16384
#define CDIM 256
#define KSPLIT 8
#define TAU 0.1f
#define IDX_INF 0x7fffffff

typedef __attribute__((ext_vector_type(8))) short bf16x8;
typedef __attribute__((ext_vector_type(4))) float f32x4;

#define AS1 __attribute__((address_space(1)))
#define AS3 __attribute__((address_space(3)))

__device__ __forceinline__ void gl_lds16(const void* g, void* l) {
  __builtin_amdgcn_global_load_lds((const AS1 unsigned int*)g,
                                   (AS3 unsigned int*)l, 16, 0, 0);
}

__device__ inline ushort f2bf(float f) {
  unsigned u = __float_as_uint(f);
  unsigned r = (u + 0x7fffu + ((u >> 16) & 1u)) >> 16;
  return (ushort)r;
}

// merge other top-2 (ob,oi,os,osi) into mine (b,i,s,si); order by (value, index)
__device__ inline void top2_merge(float& b, int& i, float& s, int& si,
                                  float ob, int oi, float os, int osi) {
  if (ob < b || (ob == b && oi < i)) {
    if (b < os || (b == os && i < osi)) { s = b; si = i; }
    else { s = os; si = osi; }
    b = ob; i = oi;
  } else {
    if (ob < s || (ob == s && oi < si)) { s = ob; si = oi; }
  }
}

// ---------------- enorm: ||e_k||^2 fp32 + exact fp64 ----------------
__global__ void vq_enorm_kernel(const float* __restrict__ emb,
                                float* __restrict__ enorm,
                                double* __restrict__ enormd) {
  __shared__ double sd[4][64];
  int tid = threadIdx.x;
  int kk = tid & 63, cg = tid >> 6;
  int k = blockIdx.x * 64 + kk;
  double s = 0.0;
  for (int c = cg * 64; c < cg * 64 + 64; ++c) {
    float v = emb[(size_t)c * VOCAB + k];
    s += (double)v * (double)v;
  }
  sd[cg][kk] = s;
  __syncthreads();
  if (cg == 0) {
    double t = sd[0][kk] + sd[1][kk] + sd[2][kk] + sd[3][kk];
    enorm[k] = (float)t;
    enormd[k] = t;
  }
}

// ---------------- fused: transpose emb -> embT fp32 AND emit eb bf16 granules ----------------
// eb chunk layout: per sp 64 chunks (kt*8+cc) of 512 granules (8 KB each).
// granule (r, s): code c_local = r*2 + (s>>2) (within kt's 128 codes),
// dims-group g = ((s&3) - r)&3, dims = cc*32 + g*8.
__global__ void vq_prep_embT_kernel(const float* __restrict__ emb,
                                    float* __restrict__ embT,
                                    ushort* __restrict__ eb) {
  __shared__ float t[32][33];
  int bc = blockIdx.x & 7;    // dims block (cc)
  int bk = blockIdx.x >> 3;   // code block
  int lx = threadIdx.x & 31, lyq = threadIdx.x >> 5;
#pragma unroll
  for (int yy = 0; yy < 4; ++yy) {
    int y = lyq * 4 + yy;
    t[y][lx] = emb[(size_t)(bc * 32 + y) * VOCAB + bk * 32 + lx];
  }
  __syncthreads();
#pragma unroll
  for (int yy = 0; yy < 4; ++yy) {
    int y = lyq * 4 + yy;
    embT[(size_t)(bk * 32 + y) * CDIM + bc * 32 + lx] = t[lx][y];
  }
  // granule emission: 128 granules (32 codes x 4 g) for cc = bc
  if (threadIdx.x < 128) {
    int cx = threadIdx.x >> 2, g = threadIdx.x & 3;
    int k = bk * 32 + cx;
    int sp = k >> 10, c_sp = k & 1023;
    int kt = c_sp >> 7, c_local = c_sp & 127;
    int r = c_local >> 1;
    int s = ((c_local & 1) << 2) | ((g + r) & 3);
    size_t ga = (size_t)sp * 32768 + (size_t)(kt * 8 + bc) * 512 + r * 8 + s;
    bf16x8 h;
#pragma unroll
    for (int j = 0; j < 8; ++j) h[j] = (short)f2bf(t[g * 8 + j][cx]);
    *(bf16x8*)(eb + ga * 8) = h;
  }
}

// ---------------- pack -2x -> bf16 pair-swizzled 128-row strips ----------------
// granule u: rb=u>>12; o=u&4095; cc=o>>9; r=(o>>3)&63; s=o&7
// row = rb*128 + r*2 + (s>>2); g = ((s&3) - r)&3; dims = cc*32 + g*8
__global__ void vq_pack_x_kernel(const float* __restrict__ x,
                                 ushort* __restrict__ xb) {
  int u = blockIdx.x * 256 + threadIdx.x;
  int rb = u >> 12;
  int o = u & 4095;
  int cc = o >> 9, r = (o >> 3) & 63, s = o & 7;
  int row = rb * 128 + r * 2 + (s >> 2);
  int g = ((s & 3) - r) & 3;
  int dims = cc * 32 + g * 8;
  const float* src = x + (size_t)row * CDIM + dims;
  float4 v0 = *(const float4*)src;
  float4 v1 = *(const float4*)(src + 4);
  float a[8] = {v0.x, v0.y, v0.z, v0.w, v1.x, v1.y, v1.z, v1.w};
  bf16x8 h;
#pragma unroll
  for (int j = 0; j < 8; ++j) h[j] = (short)f2bf(-2.0f * a[j]);
  *(bf16x8*)(xb + (size_t)u * 8) = h;
}

// ---------------- bf16 MFMA distance: 128-row blocks (halved B-traffic) ----------------
// block = 4 waves (2x2), tile 128 rows x 1024 codes (split sp).
// A resident 64KB; B streamed as 8KB chunks (128 codes x 32 dims), double-buffered.
// r4-proven __syncthreads rhythm; r8-proven pair-swizzle (0 conflicts).
__global__ __launch_bounds__(256, 2) void vq_dist_kernel(
    const ushort* __restrict__ xb, const ushort* __restrict__ eb,
    const float* __restrict__ enorm,
    float4* __restrict__ pkd, int4* __restrict__ pki) {
  __shared__ ushort Abuf[32768];        // 64 KB: [cc8][r64][s8] granules
  __shared__ ushort Bbuf[2][4096];      // 2 x 8 KB: [r64][s8]

  const int tid = threadIdx.x;
  const int lane = tid & 63, wid = tid >> 6;
  const int wr = wid >> 1, wc = wid & 1;   // 2x2 wave grid
  const int l15 = lane & 15, lg = lane >> 4;
  const int rb = blockIdx.x >> 3, sp = blockIdx.x & 7;
  const int m0 = rb * 128;

  const ushort* xs = xb + (size_t)rb * 32768;     // 64 KB A strip
  const ushort* ebb = eb + (size_t)sp * 262144;   // 64 chunks x 4096 ushorts

  // prologue: A (16 insts/wave) + B chunk 0 (2 insts/wave)
#pragma unroll
  for (int i = 0; i < 16; ++i)
    gl_lds16(xs + (wid * 16 + i) * 512 + lane * 8, &Abuf[(wid * 16 + i) * 512]);
#pragma unroll
  for (int i = 0; i < 2; ++i)
    gl_lds16(ebb + (wid * 2 + i) * 512 + lane * 8, &Bbuf[0][(wid * 2 + i) * 512]);

  // hoisted LDS byte offsets (pair-swizzle, measured conflict-free in r8)
  uint offA[4], offB[4];
#pragma unroll
  for (int mf = 0; mf < 4; ++mf) {
    int row = wr * 64 + mf * 16 + l15;
    int r = row >> 1;
    int s = ((row & 1) << 2) | ((lg + r) & 3);
    offA[mf] = r * 128 + s * 16;
  }
#pragma unroll
  for (int nf = 0; nf < 4; ++nf) {
    int c = wc * 64 + nf * 16 + l15;
    int r = c >> 1;
    int s = ((c & 1) << 2) | ((lg + r) & 3);
    offB[nf] = r * 128 + s * 16;
  }

  float bv[16];
  int bi[16];
#pragma unroll
  for (int s = 0; s < 16; ++s) { bv[s] = FLT_MAX; bi[s] = 0; }

  f32x4 acc[4][4];
  float enf[4];

  for (int kt = 0; kt < 8; ++kt) {
#pragma unroll
    for (int cc = 0; cc < 8; ++cc) {
      __syncthreads();   // chunk (kt,cc) resident; prior reads of other buf done
      // stage next chunk into the other buffer (lands during this compute)
      if (kt < 7 || cc < 7) {
        const ushort* src = ebb + (size_t)(kt * 8 + cc + 1) * 4096;
        ushort* dst = &Bbuf[(cc + 1) & 1][0];
#pragma unroll
        for (int i = 0; i < 2; ++i)
          gl_lds16(src + (wid * 2 + i) * 512 + lane * 8, dst + (wid * 2 + i) * 512);
      }
      if (cc == 0) {
#pragma unroll
        for (int mf = 0; mf < 4; ++mf)
#pragma unroll
          for (int nf = 0; nf < 4; ++nf) acc[mf][nf] = (f32x4)0.f;
      }
      const char* Ab = (const char*)Abuf + cc * 8192;
      const char* Bb = (const char*)&Bbuf[cc & 1][0];
      bf16x8 af[4], bfr[4];
#pragma unroll
      for (int mf = 0; mf < 4; ++mf) af[mf] = *(const bf16x8*)(Ab + offA[mf]);
#pragma unroll
      for (int nf = 0; nf < 4; ++nf) bfr[nf] = *(const bf16x8*)(Bb + offB[nf]);
#pragma unroll
      for (int mf = 0; mf < 4; ++mf)
#pragma unroll
        for (int nf = 0; nf < 4; ++nf)
          acc[mf][nf] = __builtin_amdgcn_mfma_f32_16x16x32_bf16(af[mf], bfr[nf], acc[mf][nf], 0, 0, 0);
      if (cc == 6) {   // issue enorm loads one interval early
#pragma unroll
        for (int nf = 0; nf < 4; ++nf)
          enf[nf] = enorm[sp * 1024 + kt * 128 + wc * 64 + nf * 16 + l15];
      }
      if (cc == 7) {
        // fold kt's distances into per-stream minima (strict < = first occurrence)
#pragma unroll
        for (int nf = 0; nf < 4; ++nf) {
          int n = sp * 1024 + kt * 128 + wc * 64 + nf * 16 + l15;
#pragma unroll
          for (int mf = 0; mf < 4; ++mf)
#pragma unroll
            for (int r = 0; r < 4; ++r) {
              float d = acc[mf][nf][r] + enf[nf];
              int s = mf * 4 + r;
              if (d < bv[s]) { bv[s] = d; bi[s] = n; }
            }
        }
      }
    }
  }

  // per-stream top-2 across the 16 column-lanes (in-register)
  __syncthreads();                             // Bbuf free for overlay below
  float* msd = (float*)&Bbuf[0][0];            // [e2][wc2][row128] floats
  int* msi = (int*)&Bbuf[0][0] + 512;          // [e2][wc2][row128] ints
#pragma unroll
  for (int mf = 0; mf < 4; ++mf)
#pragma unroll
    for (int r = 0; r < 4; ++r) {
      int s = mf * 4 + r;
      float b = bv[s], sec = FLT_MAX;
      int i = bi[s], si = IDX_INF;
#pragma unroll
      for (int m = 1; m < 16; m <<= 1) {
        float ob = __shfl_xor(b, m, 64);
        float os = __shfl_xor(sec, m, 64);
        int oi = __shfl_xor(i, m, 64);
        int osi = __shfl_xor(si, m, 64);
        top2_merge(b, i, sec, si, ob, oi, os, osi);
      }
      if (l15 == 0) {
        int row = wr * 64 + mf * 16 + lg * 4 + r;
        msd[(0 * 2 + wc) * 128 + row] = b;   msi[(0 * 2 + wc) * 128 + row] = i;
        msd[(1 * 2 + wc) * 128 + row] = sec; msi[(1 * 2 + wc) * 128 + row] = si;
      }
    }
  __syncthreads();
  if (tid < 128) {
    float d[4] = {FLT_MAX, FLT_MAX, FLT_MAX, FLT_MAX};
    int ix[4] = {IDX_INF, IDX_INF, IDX_INF, IDX_INF};
#pragma unroll
    for (int wcq = 0; wcq < 2; ++wcq)
#pragma unroll
      for (int e = 0; e < 2; ++e) {
        float a = msd[(e * 2 + wcq) * 128 + tid];
        int ai = msi[(e * 2 + wcq) * 128 + tid];
#pragma unroll
        for (int q = 0; q < 4; ++q) {
          bool lt = (a < d[q]) || (a == d[q] && ai < ix[q]);
          float td = lt ? d[q] : a;
          int ti = lt ? ix[q] : ai;
          d[q] = lt ? a : d[q];
          ix[q] = lt ? ai : ix[q];
          a = td; ai = ti;
        }
      }
    pkd[(size_t)sp * MTOT + m0 + tid] = make_float4(d[0], d[1], d[2], d[3]);
    pki[(size_t)sp * MTOT + m0 + tid] = make_int4(ix[0], ix[1], ix[2], ix[3]);
  }
}

// ---------------- merge 32 candidates + fp64 rescue + gather (1 wave / row) ----------------
__global__ void vq_gather_kernel(
    const float* __restrict__ x, const float* __restrict__ embT,
    const double* __restrict__ enormd,
    const float4* __restrict__ pkd, const int4* __restrict__ pki,
    float* __restrict__ out, int* __restrict__ counts, float* __restrict__ ssep) {
  const int wid = threadIdx.x >> 6, lane = threadIdx.x & 63;
  const int m = blockIdx.x * 4 + wid;

  const float4 xq = *(const float4*)(x + (size_t)m * CDIM + lane * 4);

  float bd = FLT_MAX, sd = FLT_MAX;
  int bidx = IDX_INF;
#pragma unroll
  for (int sp2 = 0; sp2 < KSPLIT; ++sp2) {
    float4 dv = pkd[(size_t)sp2 * MTOT + m];
    int4 iv = pki[(size_t)sp2 * MTOT + m];
    float ds[4] = {dv.x, dv.y, dv.z, dv.w};
    int is[4] = {iv.x, iv.y, iv.z, iv.w};
#pragma unroll
    for (int j = 0; j < 4; ++j) {
      float dj = ds[j];
      int ij = is[j];
      if (dj < bd || (dj == bd && ij < bidx)) { sd = bd; bd = dj; bidx = ij; }
      else sd = fminf(sd, dj);
    }
  }
  int best = bidx;
  if (sd - bd < TAU) {   // ambiguous: exact fp64 over all 32 candidates (wave-uniform)
    double bD = DBL_MAX;
    int bn = IDX_INF;
    for (int sp2 = 0; sp2 < KSPLIT; ++sp2) {
      int4 iv = pki[(size_t)sp2 * MTOT + m];
      int is[4] = {iv.x, iv.y, iv.z, iv.w};
#pragma unroll
      for (int j = 0; j < 4; ++j) {
        int cj = is[j];
        const float4 ev = *(const float4*)(embT + (size_t)cj * CDIM + lane * 4);
        double p = (double)xq.x * ev.x + (double)xq.y * ev.y
                 + (double)xq.z * ev.z + (double)xq.w * ev.w;
#pragma unroll
        for (int off = 1; off < 64; off <<= 1) p += __shfl_xor(p, off, 64);
        double dj = enormd[cj] - 2.0 * p;
        if (dj < bD || (dj == bD && cj < bn)) { bD = dj; bn = cj; }
      }
    }
    best = bn;
  }
  const float4 ev = *(const float4*)(embT + (size_t)best * CDIM + lane * 4);
  *(float4*)(out + (size_t)m * CDIM + lane * 4) = ev;
  float dx = ev.x - xq.x, dy = ev.y - xq.y, dz = ev.z - xq.z, dw = ev.w - xq.w;
  float v = dx * dx + dy * dy + dz * dz + dw * dw;
#pragma unroll
  for (int off = 32; off > 0; off >>= 1) v += __shfl_down(v, off, 64);
  if (lane == 0) {
    ssep[m] = v;
    atomicAdd(&counts[best], 1);
  }
}

// ---------------- loss + perplexity, two-stage deterministic ----------------
__global__ void vq_final1_kernel(const float* __restrict__ ssep,
                                 const int* __restrict__ counts,
                                 double* __restrict__ part) {
  __shared__ double red[256];
  const int tid = threadIdx.x, b = blockIdx.x;
  red[tid] = (double)ssep[b * 256 + tid];
  __syncthreads();
  for (int off = 128; off > 0; off >>= 1) {
    if (tid < off) red[tid] += red[tid + off];
    __syncthreads();
  }
  if (tid == 0) part[b] = red[0];
  __syncthreads();
  double e = 0.0;
  if (tid < 128) {
    double p = (double)counts[b * 128 + tid] / (double)MTOT;
    e = p * log(p + 1e-10);
  }
  red[tid] = e;
  __syncthreads();
  for (int off = 128; off > 0; off >>= 1) {
    if (tid < off) red[tid] += red[tid + off];
    __syncthreads();
  }
  if (tid == 0) part[64 + b] = red[0];
}

__global__ void vq_final2_kernel(const double* __restrict__ part,
                                 float* __restrict__ out) {
  const int lane = threadIdx.x;   // 64 threads
  double s = part[lane], e = part[64 + lane];
#pragma unroll
  for (int off = 32; off > 0; off >>= 1) {
    s += __shfl_down(s, off, 64);
    e += __shfl_down(e, off, 64);
  }
  if (lane == 0) {
    out[(size_t)MTOT * CDIM] = (float)(1.25 * s / (double)((size_t)MTOT * CDIM));
    out[(size_t)MTOT * CDIM + 1] = (float)exp(-e);
  }
}

extern "C" void kernel_launch(void* const* d_in, const int* in_sizes, int n_in,
                              void* d_out, int out_size, void* d_ws, size_t ws_size,
                              hipStream_t stream) {
  const float* x = (const float*)d_in[0];
  const float* emb = (const float*)d_in[1];
  float* out = (float*)d_out;
  char* ws = (char*)d_ws;

  // workspace layout (bytes)
  double* enormd = (double*)(ws);                 //        0: 65536
  float* enorm   = (float*)(ws + 65536);          //    65536: 32768
  float4* pkd    = (float4*)(ws + 98304);         //    98304: 2097152
  int4* pki      = (int4*)(ws + 2195456);         //  2195456: 2097152
  int* counts    = (int*)(ws + 4292608);          //  4292608: 32768
  float* ssep    = (float*)(ws + 4325376);        //  4325376: 65536
  double* part   = (double*)(ws + 4390912);       //  4390912: 1024
  float* embT    = (float*)(ws + 4391936);        //  4391936: 8388608
  ushort* xb     = (ushort*)(ws + 12780544);      // 12780544: 8388608
  ushort* eb     = (ushort*)(ws + 21169152);      // 21169152: 4194304
  // total 25363456 bytes (< 35 MB proven available in rounds 1-9)

  hipMemsetAsync(counts, 0, VOCAB * sizeof(int), stream);
  vq_enorm_kernel<<<VOCAB / 64, 256, 0, stream>>>(emb, enorm, enormd);
  vq_prep_embT_kernel<<<(VOCAB / 32) * (CDIM / 32), 256, 0, stream>>>(emb, embT, eb);
  vq_pack_x_kernel<<<(MTOT * CDIM / 8) / 256, 256, 0, stream>>>(x, xb);
  vq_dist_kernel<<<(MTOT / 128) * KSPLIT, 256, 0, stream>>>(xb, eb, enorm, pkd, pki);
  vq_gather_kernel<<<MTOT / 4, 256, 0, stream>>>(x, embT, enormd, pkd, pki,
                                                 out, counts, ssep);
  vq_final1_kernel<<<64, 256, 0, stream>>>(ssep, counts, part);
  vq_final2_kernel<<<1, 64, 0, stream>>>(part, out);
}

// Round 11
// 220.809 us; speedup vs baseline: 1.2431x; 1.0261x over previous
//
#include <hip/hip_runtime.h>
#include <cfloat>
#include <cmath>

#define VOCAB 8192
#define MTOT 16384
#define CDIM 256
#define KSPLIT 8
#define TAU 0.1f
#define IDX_INF 0x7fffffff

typedef __attribute__((ext_vector_type(8))) short bf16x8;
typedef __attribute__((ext_vector_type(4))) float f32x4;

#define AS1 __attribute__((address_space(1)))
#define AS3 __attribute__((address_space(3)))

__device__ __forceinline__ void gl_lds16(const void* g, void* l) {
  __builtin_amdgcn_global_load_lds((const AS1 unsigned int*)g,
                                   (AS3 unsigned int*)l, 16, 0, 0);
}

__device__ inline ushort f2bf(float f) {
  unsigned u = __float_as_uint(f);
  unsigned r = (u + 0x7fffu + ((u >> 16) & 1u)) >> 16;
  return (ushort)r;
}

// merge other top-2 (ob,oi,os,osi) into mine (b,i,s,si); order by (value, index)
__device__ inline void top2_merge(float& b, int& i, float& s, int& si,
                                  float ob, int oi, float os, int osi) {
  if (ob < b || (ob == b && oi < i)) {
    if (b < os || (b == os && i < osi)) { s = b; si = i; }
    else { s = os; si = osi; }
    b = ob; i = oi;
  } else {
    if (ob < s || (ob == s && oi < si)) { s = ob; si = oi; }
  }
}

// ---------------- enorm: ||e_k||^2 fp32 + exact fp64 ----------------
__global__ void vq_enorm_kernel(const float* __restrict__ emb,
                                float* __restrict__ enorm,
                                double* __restrict__ enormd) {
  __shared__ double sd[4][64];
  int tid = threadIdx.x;
  int kk = tid & 63, cg = tid >> 6;
  int k = blockIdx.x * 64 + kk;
  double s = 0.0;
  for (int c = cg * 64; c < cg * 64 + 64; ++c) {
    float v = emb[(size_t)c * VOCAB + k];
    s += (double)v * (double)v;
  }
  sd[cg][kk] = s;
  __syncthreads();
  if (cg == 0) {
    double t = sd[0][kk] + sd[1][kk] + sd[2][kk] + sd[3][kk];
    enorm[k] = (float)t;
    enormd[k] = t;
  }
}

// ---------------- fused: transpose emb -> embT fp32 AND emit eb bf16 granules ----------------
// eb layout: per sp 64 chunks (cg*4+kc) of 512 granules (8 KB).
// chunk granule index = ks*256 + r*8 + s where code c_local = k&63, r=c_local>>1,
// s = ((c_local&1)<<2)|((lg + r)&3); dims = kc*64 + ks*32 + lg*8.
__global__ void vq_prep_embT_kernel(const float* __restrict__ emb,
                                    float* __restrict__ embT,
                                    ushort* __restrict__ eb) {
  __shared__ float t[32][33];
  int bc = blockIdx.x & 7;    // dims block of 32
  int bk = blockIdx.x >> 3;   // code block of 32
  int lx = threadIdx.x & 31, lyq = threadIdx.x >> 5;
#pragma unroll
  for (int yy = 0; yy < 4; ++yy) {
    int y = lyq * 4 + yy;
    t[y][lx] = emb[(size_t)(bc * 32 + y) * VOCAB + bk * 32 + lx];
  }
  __syncthreads();
#pragma unroll
  for (int yy = 0; yy < 4; ++yy) {
    int y = lyq * 4 + yy;
    embT[(size_t)(bk * 32 + y) * CDIM + bc * 32 + lx] = t[lx][y];
  }
  // granule emission: 128 granules (32 codes x 4 lg) for this (bk, bc) tile
  if (threadIdx.x < 128) {
    int cx = threadIdx.x >> 2, lg = threadIdx.x & 3;
    int k = bk * 32 + cx;
    int sp = k >> 10;
    int cg = (k >> 6) & 15;
    int c_local = k & 63;
    int kc = bc >> 1, ks = bc & 1;
    int r = c_local >> 1;
    int s = ((c_local & 1) << 2) | ((lg + r) & 3);
    size_t gi = ((size_t)(sp * 64 + cg * 4 + kc)) * 512 + ks * 256 + r * 8 + s;
    bf16x8 h;
#pragma unroll
    for (int j = 0; j < 8; ++j) h[j] = (short)f2bf(t[lg * 8 + j][cx]);
    *(bf16x8*)(eb + gi * 8) = h;
  }
}

// ---------------- pack -2x -> bf16 register-frag-ordered strips ----------------
// granule u: strip = u>>11 (64 rows); f = (u>>6)&31 = mf*8+kg; lane = u&63.
// row = strip*64 + mf*16 + (lane&15); dims = kg*32 + (lane>>4)*8
__global__ void vq_pack_x_kernel(const float* __restrict__ x,
                                 ushort* __restrict__ xb) {
  int u = blockIdx.x * 256 + threadIdx.x;
  int strip = u >> 11;
  int f = (u >> 6) & 31;
  int lane = u & 63;
  int mf = f >> 3, kg = f & 7;
  int lg = lane >> 4, l15 = lane & 15;
  int row = strip * 64 + mf * 16 + l15;
  int dims = kg * 32 + lg * 8;
  const float* src = x + (size_t)row * CDIM + dims;
  float4 v0 = *(const float4*)src;
  float4 v1 = *(const float4*)(src + 4);
  float a[8] = {v0.x, v0.y, v0.z, v0.w, v1.x, v1.y, v1.z, v1.w};
  bf16x8 h;
#pragma unroll
  for (int j = 0; j < 8; ++j) h[j] = (short)f2bf(-2.0f * a[j]);
  *(bf16x8*)(xb + (size_t)u * 8) = h;
}

// ---------------- bf16 MFMA distance: A in registers, 256-row blocks, 1 round ----------------
// block = 4 waves, each owning 64 rows with A resident in 128 VGPRs (32 frags).
// B (1024 codes, split sp) streamed as 64 x 8KB chunks (64 codes x 64 dims),
// double-buffered with the proven __syncthreads rhythm. Only 16 KB LDS.
__global__ __launch_bounds__(256, 2) void vq_dist_kernel(
    const ushort* __restrict__ xb, const ushort* __restrict__ eb,
    const float* __restrict__ enorm,
    float4* __restrict__ pkd, int4* __restrict__ pki) {
  __shared__ ushort Bbuf[2][4096];      // 2 x 8 KB

  const int tid = threadIdx.x;
  const int lane = tid & 63, wid = tid >> 6;
  const int l15 = lane & 15, lg = lane >> 4;
  const int rb = blockIdx.x >> 3, sp = blockIdx.x & 7;
  const int mw = rb * 256 + wid * 64;   // this wave's first row

  // A into registers: 32 frags (64 rows x 256 dims), coalesced 16B/lane loads
  bf16x8 af[4][8];
  {
    const bf16x8* xs4 = (const bf16x8*)xb + (size_t)(rb * 4 + wid) * 2048 + lane;
#pragma unroll
    for (int mf = 0; mf < 4; ++mf)
#pragma unroll
      for (int kg = 0; kg < 8; ++kg)
        af[mf][kg] = xs4[(mf * 8 + kg) * 64];
  }

  const ushort* ebb = eb + (size_t)sp * 262144;   // 64 chunks x 4096 ushorts

  // stage B chunk 0
#pragma unroll
  for (int i = 0; i < 2; ++i)
    gl_lds16(ebb + (wid * 2 + i) * 512 + lane * 8, &Bbuf[0][(wid * 2 + i) * 512]);

  // hoisted B LDS byte offsets (pair-swizzle, proven conflict-free)
  uint offB[4];
#pragma unroll
  for (int nf = 0; nf < 4; ++nf) {
    int c = nf * 16 + l15;
    int r = c >> 1;
    int s = ((c & 1) << 2) | ((lg + r) & 3);
    offB[nf] = r * 128 + s * 16;
  }

  float bv[16];
  int bi[16];
#pragma unroll
  for (int s = 0; s < 16; ++s) { bv[s] = FLT_MAX; bi[s] = 0; }

  f32x4 acc[4][4];
  float enf[4];

  for (int cg = 0; cg < 16; ++cg) {
#pragma unroll
    for (int kc = 0; kc < 4; ++kc) {
      __syncthreads();   // chunk (cg,kc) resident; other buffer's reads done
      // stage next chunk into the other buffer (lands during this compute)
      if (cg < 15 || kc < 3) {
        const ushort* src = ebb + (size_t)(cg * 4 + kc + 1) * 4096;
        ushort* dst = &Bbuf[(kc + 1) & 1][0];
#pragma unroll
        for (int i = 0; i < 2; ++i)
          gl_lds16(src + (wid * 2 + i) * 512 + lane * 8, dst + (wid * 2 + i) * 512);
      }
      if (kc == 0) {
#pragma unroll
        for (int mf = 0; mf < 4; ++mf)
#pragma unroll
          for (int nf = 0; nf < 4; ++nf) acc[mf][nf] = (f32x4)0.f;
      }
      const char* Bb = (const char*)&Bbuf[kc & 1][0];
#pragma unroll
      for (int ks = 0; ks < 2; ++ks) {
        bf16x8 bfr[4];
#pragma unroll
        for (int nf = 0; nf < 4; ++nf)
          bfr[nf] = *(const bf16x8*)(Bb + ks * 4096 + offB[nf]);
#pragma unroll
        for (int mf = 0; mf < 4; ++mf)
#pragma unroll
          for (int nf = 0; nf < 4; ++nf)
            acc[mf][nf] = __builtin_amdgcn_mfma_f32_16x16x32_bf16(
                af[mf][kc * 2 + ks], bfr[nf], acc[mf][nf], 0, 0, 0);
      }
      if (kc == 2) {   // issue enorm loads one period early
#pragma unroll
        for (int nf = 0; nf < 4; ++nf)
          enf[nf] = enorm[sp * 1024 + cg * 64 + nf * 16 + l15];
      }
      if (kc == 3) {
        // fold this code-group's distances (strict < = first occurrence)
#pragma unroll
        for (int nf = 0; nf < 4; ++nf) {
          int n = sp * 1024 + cg * 64 + nf * 16 + l15;
#pragma unroll
          for (int mf = 0; mf < 4; ++mf)
#pragma unroll
            for (int r = 0; r < 4; ++r) {
              float d = acc[mf][nf][r] + enf[nf];
              int s = mf * 4 + r;
              if (d < bv[s]) { bv[s] = d; bi[s] = n; }
            }
        }
      }
    }
  }

  // per-row top-2 across the 16 column-lanes; direct global write (no LDS)
#pragma unroll
  for (int mf = 0; mf < 4; ++mf)
#pragma unroll
    for (int r = 0; r < 4; ++r) {
      int s = mf * 4 + r;
      float b = bv[s], sec = FLT_MAX;
      int i = bi[s], si = IDX_INF;
#pragma unroll
      for (int m = 1; m < 16; m <<= 1) {
        float ob = __shfl_xor(b, m, 64);
        float os = __shfl_xor(sec, m, 64);
        int oi = __shfl_xor(i, m, 64);
        int osi = __shfl_xor(si, m, 64);
        top2_merge(b, i, sec, si, ob, oi, os, osi);
      }
      if (l15 == 0) {
        int row = mw + mf * 16 + lg * 4 + r;
        // pad with FLT_MAX dists + duplicated valid indices (gather-safe)
        pkd[(size_t)sp * MTOT + row] = make_float4(b, sec, FLT_MAX, FLT_MAX);
        pki[(size_t)sp * MTOT + row] = make_int4(i, si, i, si);
      }
    }
}

// ---------------- merge 32 candidates + fp64 rescue + gather (1 wave / row) ----------------
__global__ void vq_gather_kernel(
    const float* __restrict__ x, const float* __restrict__ embT,
    const double* __restrict__ enormd,
    const float4* __restrict__ pkd, const int4* __restrict__ pki,
    float* __restrict__ out, int* __restrict__ counts, float* __restrict__ ssep) {
  const int wid = threadIdx.x >> 6, lane = threadIdx.x & 63;
  const int m = blockIdx.x * 4 + wid;

  const float4 xq = *(const float4*)(x + (size_t)m * CDIM + lane * 4);

  float bd = FLT_MAX, sd = FLT_MAX;
  int bidx = IDX_INF;
#pragma unroll
  for (int sp2 = 0; sp2 < KSPLIT; ++sp2) {
    float4 dv = pkd[(size_t)sp2 * MTOT + m];
    int4 iv = pki[(size_t)sp2 * MTOT + m];
    float ds[4] = {dv.x, dv.y, dv.z, dv.w};
    int is[4] = {iv.x, iv.y, iv.z, iv.w};
#pragma unroll
    for (int j = 0; j < 4; ++j) {
      float dj = ds[j];
      int ij = is[j];
      if (dj < bd || (dj == bd && ij < bidx)) { sd = bd; bd = dj; bidx = ij; }
      else sd = fminf(sd, dj);
    }
  }
  int best = bidx;
  if (sd - bd < TAU) {   // ambiguous: exact fp64 over all candidates (wave-uniform)
    double bD = DBL_MAX;
    int bn = IDX_INF;
    for (int sp2 = 0; sp2 < KSPLIT; ++sp2) {
      int4 iv = pki[(size_t)sp2 * MTOT + m];
      int is[4] = {iv.x, iv.y, iv.z, iv.w};
#pragma unroll
      for (int j = 0; j < 4; ++j) {
        int cj = is[j];
        const float4 ev = *(const float4*)(embT + (size_t)cj * CDIM + lane * 4);
        double p = (double)xq.x * ev.x + (double)xq.y * ev.y
                 + (double)xq.z * ev.z + (double)xq.w * ev.w;
#pragma unroll
        for (int off = 1; off < 64; off <<= 1) p += __shfl_xor(p, off, 64);
        double dj = enormd[cj] - 2.0 * p;
        if (dj < bD || (dj == bD && cj < bn)) { bD = dj; bn = cj; }
      }
    }
    best = bn;
  }
  const float4 ev = *(const float4*)(embT + (size_t)best * CDIM + lane * 4);
  *(float4*)(out + (size_t)m * CDIM + lane * 4) = ev;
  float dx = ev.x - xq.x, dy = ev.y - xq.y, dz = ev.z - xq.z, dw = ev.w - xq.w;
  float v = dx * dx + dy * dy + dz * dz + dw * dw;
#pragma unroll
  for (int off = 32; off > 0; off >>= 1) v += __shfl_down(v, off, 64);
  if (lane == 0) {
    ssep[m] = v;
    atomicAdd(&counts[best], 1);
  }
}

// ---------------- loss + perplexity, single fused kernel (1 block) ----------------
__global__ void vq_final_kernel(const float* __restrict__ ssep,
                                const int* __restrict__ counts,
                                float* __restrict__ out) {
  __shared__ double red[256];
  const int tid = threadIdx.x;
  double s = 0.0;
  for (int i = tid; i < MTOT; i += 256) s += (double)ssep[i];
  red[tid] = s;
  __syncthreads();
  for (int off = 128; off > 0; off >>= 1) {
    if (tid < off) red[tid] += red[tid + off];
    __syncthreads();
  }
  double sse = red[0];
  __syncthreads();
  double e = 0.0;
  for (int k = tid; k < VOCAB; k += 256) {
    double p = (double)counts[k] / (double)MTOT;
    e += p * log(p + 1e-10);
  }
  red[tid] = e;
  __syncthreads();
  for (int off = 128; off > 0; off >>= 1) {
    if (tid < off) red[tid] += red[tid + off];
    __syncthreads();
  }
  if (tid == 0) {
    out[(size_t)MTOT * CDIM] = (float)(1.25 * sse / (double)((size_t)MTOT * CDIM));
    out[(size_t)MTOT * CDIM + 1] = (float)exp(-red[0]);
  }
}

extern "C" void kernel_launch(void* const* d_in, const int* in_sizes, int n_in,
                              void* d_out, int out_size, void* d_ws, size_t ws_size,
                              hipStream_t stream) {
  const float* x = (const float*)d_in[0];
  const float* emb = (const float*)d_in[1];
  float* out = (float*)d_out;
  char* ws = (char*)d_ws;

  // workspace layout (bytes)
  double* enormd = (double*)(ws);                 //        0: 65536
  float* enorm   = (float*)(ws + 65536);          //    65536: 32768
  float4* pkd    = (float4*)(ws + 98304);         //    98304: 2097152
  int4* pki      = (int4*)(ws + 2195456);         //  2195456: 2097152
  int* counts    = (int*)(ws + 4292608);          //  4292608: 32768
  float* ssep    = (float*)(ws + 4325376);        //  4325376: 65536
  float* embT    = (float*)(ws + 4391936);        //  4391936: 8388608
  ushort* xb     = (ushort*)(ws + 12780544);      // 12780544: 8388608
  ushort* eb     = (ushort*)(ws + 21169152);      // 21169152: 4194304
  // total 25363456 bytes (< 35 MB proven available in rounds 1-10)

  hipMemsetAsync(counts, 0, VOCAB * sizeof(int), stream);
  vq_enorm_kernel<<<VOCAB / 64, 256, 0, stream>>>(emb, enorm, enormd);
  vq_prep_embT_kernel<<<(VOCAB / 32) * (CDIM / 32), 256, 0, stream>>>(emb, embT, eb);
  vq_pack_x_kernel<<<(MTOT * CDIM / 8) / 256, 256, 0, stream>>>(x, xb);
  vq_dist_kernel<<<(MTOT / 256) * KSPLIT, 256, 0, stream>>>(xb, eb, enorm, pkd, pki);
  vq_gather_kernel<<<MTOT / 4, 256, 0, stream>>>(x, embT, enormd, pkd, pki,
                                                 out, counts, ssep);
  vq_final_kernel<<<1, 256, 0, stream>>>(ssep, counts, out);
}